// Round 2
// baseline (3731.407 us; speedup 1.0000x reference)
//
#include <hip/hip_runtime.h>
#include <hip/hip_bf16.h>

#define NN 50000
#define NE 500000

// order-preserving float->uint encoding for atomicMax-based segment_max
__device__ __forceinline__ unsigned enc_ord(float x){
  unsigned b = __float_as_uint(x);
  return (b & 0x80000000u) ? ~b : (b | 0x80000000u);
}
__device__ __forceinline__ float dec_ord(unsigned k){
  unsigned b = (k & 0x80000000u) ? (k ^ 0x80000000u) : ~k;
  return __uint_as_float(b);
}
#define ENC_NEG_INF 0x007fffffu  // enc_ord(-inf)

__global__ void k_embed(const int* __restrict__ nt, const float* __restrict__ table,
                        float* __restrict__ nf){
  int i = blockIdx.x * 256 + threadIdx.x;
  if (i >= NN * 128) return;
  nf[i] = table[nt[i >> 7] * 128 + (i & 127)];
}

__global__ void k_init(float* __restrict__ h_new, unsigned* __restrict__ m_enc,
                       float* __restrict__ s){
  int i = blockIdx.x * 256 + threadIdx.x;
  if (i < NN * 256) h_new[i] = 0.f;
  if (i < NN * 4){ m_enc[i] = ENC_NEG_INF; s[i] = 0.f; }
}

// C[M x Nc] = A[M x K] @ W[K x Nc] (+ bias). fp32, fp32 accum.
// grid: (M/16, Nc/128), block 256. Each thread: col c, 8 rows.
__global__ __launch_bounds__(256) void k_gemm(
    const float* __restrict__ A, const float* __restrict__ W,
    const float* __restrict__ bias, float* __restrict__ C,
    int M, int K, int Nc){
  __shared__ float As[16][64];
  __shared__ float Ws[64][128];
  int tid = threadIdx.x;
  int row0 = blockIdx.x * 16;
  int col0 = blockIdx.y * 128;
  int c  = tid & 127;
  int rg = tid >> 7;            // 0..1
  float acc[8] = {0,0,0,0,0,0,0,0};
  for (int k0 = 0; k0 < K; k0 += 64){
    // A tile: 16x64 floats = 256 float4 -> 1 per thread
    {
      int r = tid >> 4, kk = (tid & 15) * 4;
      int gr = row0 + r;
      float4 v = make_float4(0.f, 0.f, 0.f, 0.f);
      if (gr < M) v = *reinterpret_cast<const float4*>(A + (size_t)gr * K + k0 + kk);
      *reinterpret_cast<float4*>(&As[r][kk]) = v;
    }
    // W tile: 64x128 floats = 2048 float4 -> 8 per thread
    #pragma unroll
    for (int j = 0; j < 8; ++j){
      int q = tid + j * 256;
      int kk = q >> 5, cc = (q & 31) * 4;
      *reinterpret_cast<float4*>(&Ws[kk][cc]) =
          *reinterpret_cast<const float4*>(W + (size_t)(k0 + kk) * Nc + col0 + cc);
    }
    __syncthreads();
    for (int kk = 0; kk < 64; kk += 4){
      float w0 = Ws[kk][c];
      float w1 = Ws[kk+1][c];
      float w2 = Ws[kk+2][c];
      float w3 = Ws[kk+3][c];
      #pragma unroll
      for (int r = 0; r < 8; ++r){
        float4 av = *reinterpret_cast<const float4*>(&As[rg*8 + r][kk]);
        acc[r] += av.x*w0 + av.y*w1 + av.z*w2 + av.w*w3;
      }
    }
    __syncthreads();
  }
  #pragma unroll
  for (int r = 0; r < 8; ++r){
    int gr = row0 + rg*8 + r;
    if (gr < M){
      float v = acc[r];
      if (bias) v += bias[col0 + c];
      C[(size_t)gr * Nc + col0 + c] = v;
    }
  }
}

// Per edge (128 cols): F = lrelu(F + f_ni[src] + f_nj[dst] + bias); logits[e][h] = <F_h, attn_h>
__global__ __launch_bounds__(256) void k_edge_build(
    float* __restrict__ F, const float* __restrict__ f_ni, const float* __restrict__ f_nj,
    const float* __restrict__ bias, const float* __restrict__ attn,
    const int* __restrict__ src, const int* __restrict__ dst,
    float* __restrict__ logits){
  int tid = threadIdx.x;
  int e = blockIdx.x * 2 + (tid >> 7);
  if (e >= NE) return;
  int c = tid & 127;
  int sN = src[e], dN = dst[e];
  size_t ix = (size_t)e * 128 + c;
  float v = F[ix] + f_ni[sN*128 + c] + f_nj[dN*128 + c] + bias[c];
  v = (v >= 0.f) ? v : 0.01f * v;
  F[ix] = v;
  // attn is (4,32) flattened: head h = c>>5 uses attn[h*32 + (c&31)] == attn[c]
  float p = v * attn[c];
  p += __shfl_xor(p, 16, 64);
  p += __shfl_xor(p, 8, 64);
  p += __shfl_xor(p, 4, 64);
  p += __shfl_xor(p, 2, 64);
  p += __shfl_xor(p, 1, 64);
  if ((c & 31) == 0) logits[e * 4 + (c >> 5)] = p;
}

__global__ void k_segmax(const float* __restrict__ logits, const int* __restrict__ dst,
                         unsigned* __restrict__ m_enc){
  int i = blockIdx.x * 256 + threadIdx.x;
  if (i >= NE * 4) return;
  atomicMax(&m_enc[dst[i >> 2] * 4 + (i & 3)], enc_ord(logits[i]));
}

__global__ void k_expsum(float* __restrict__ logits, const int* __restrict__ dst,
                         const unsigned* __restrict__ m_enc, float* __restrict__ s){
  int i = blockIdx.x * 256 + threadIdx.x;
  if (i >= NE * 4) return;
  int q = dst[i >> 2] * 4 + (i & 3);
  float ee = expf(logits[i] - dec_ord(m_enc[q]));
  logits[i] = ee;
  atomicAdd(&s[q], ee);
}

// One block per edge: h_new[dst] += h_src[src] * alpha  (256 cols = 4 heads x 64)
__global__ __launch_bounds__(256) void k_agg(
    const float* __restrict__ eel, const float* __restrict__ s,
    const float* __restrict__ h_src, const int* __restrict__ src,
    const int* __restrict__ dst, float* __restrict__ h_new){
  int e = blockIdx.x;
  int c = threadIdx.x;
  int h = c >> 6;
  int sN = src[e], dN = dst[e];
  float alpha = eel[e * 4 + h] / s[dN * 4 + h];
  atomicAdd(&h_new[dN * 256 + c], h_src[sN * 256 + c] * alpha);
}

__global__ void k_node_elu(const float* __restrict__ h_new, float* __restrict__ out){
  int i = blockIdx.x * 256 + threadIdx.x;
  if (i >= NN * 256) return;
  float v = h_new[i];
  out[i] = v > 0.f ? v : expm1f(v);
}

__global__ void k_edge_elu(const float* __restrict__ F, float* __restrict__ out){
  size_t i = (size_t)blockIdx.x * 256 + threadIdx.x;
  if (i >= (size_t)NE * 128) return;
  float v = F[i];
  out[i] = v > 0.f ? v : expm1f(v);
}

static void run_layer(const float* nf, int in_n, const float* ef, int in_e,
                      const float* Wsrc, const float* bsrc, const float* Wni,
                      const float* Wnj, const float* Wfij, const float* attn,
                      const float* bias, const int* src, const int* dst,
                      float* f_ni, float* f_nj, float* h_src, float* F,
                      float* logits, unsigned* m_enc, float* s, float* h_new,
                      float* nf_out, float* ef_out, hipStream_t stream){
  k_gemm<<<dim3(NN/16, 1), 256, 0, stream>>>(nf, Wni, nullptr, f_ni, NN, in_n, 128);
  k_gemm<<<dim3(NN/16, 1), 256, 0, stream>>>(nf, Wnj, nullptr, f_nj, NN, in_n, 128);
  k_gemm<<<dim3(NN/16, 2), 256, 0, stream>>>(nf, Wsrc, bsrc, h_src, NN, in_n, 256);
  k_gemm<<<dim3(NE/16, 1), 256, 0, stream>>>(ef, Wfij, nullptr, F, NE, in_e, 128);
  k_init<<<(NN*256)/256, 256, 0, stream>>>(h_new, m_enc, s);
  k_edge_build<<<NE/2, 256, 0, stream>>>(F, f_ni, f_nj, bias, attn, src, dst, logits);
  k_segmax<<<(NE*4 + 255)/256, 256, 0, stream>>>(logits, dst, m_enc);
  k_expsum<<<(NE*4 + 255)/256, 256, 0, stream>>>(logits, dst, m_enc, s);
  k_agg<<<NE, 256, 0, stream>>>(logits, s, h_src, src, dst, h_new);
  k_node_elu<<<(NN*256)/256, 256, 0, stream>>>(h_new, nf_out);
  k_edge_elu<<<(NE*128)/256, 256, 0, stream>>>(F, ef_out);
}

extern "C" void kernel_launch(void* const* d_in, const int* in_sizes, int n_in,
                              void* d_out, int out_size, void* d_ws, size_t ws_size,
                              hipStream_t stream){
  const int*   node_types = (const int*)d_in[0];
  const int*   src        = (const int*)d_in[1];
  const int*   dst        = (const int*)d_in[2];
  const float* efeats     = (const float*)d_in[3];
  const float* table      = (const float*)d_in[4];
  const float* W_src0 = (const float*)d_in[5];
  const float* b_src0 = (const float*)d_in[6];
  const float* W_ni0  = (const float*)d_in[7];
  const float* W_nj0  = (const float*)d_in[8];
  const float* W_fij0 = (const float*)d_in[9];
  const float* attn0  = (const float*)d_in[10];
  const float* bias0  = (const float*)d_in[11];
  const float* W_src1 = (const float*)d_in[12];
  const float* b_src1 = (const float*)d_in[13];
  const float* W_ni1  = (const float*)d_in[14];
  const float* W_nj1  = (const float*)d_in[15];
  const float* W_fij1 = (const float*)d_in[16];
  const float* attn1  = (const float*)d_in[17];
  const float* bias1  = (const float*)d_in[18];

  char* w = (char*)d_ws;
  auto alloc = [&](size_t bytes){ void* p = (void*)w; w += (bytes + 255) & ~(size_t)255; return p; };
  float*    nf_buf = (float*)   alloc((size_t)NN * 256 * 4);
  float*    f_ni   = (float*)   alloc((size_t)NN * 128 * 4);
  float*    f_nj   = (float*)   alloc((size_t)NN * 128 * 4);
  float*    h_src  = (float*)   alloc((size_t)NN * 256 * 4);
  float*    h_new  = (float*)   alloc((size_t)NN * 256 * 4);
  unsigned* m_enc  = (unsigned*)alloc((size_t)NN * 4 * 4);
  float*    s      = (float*)   alloc((size_t)NN * 4 * 4);
  float*    logits = (float*)   alloc((size_t)NE * 4 * 4);
  float*    F      = (float*)   alloc((size_t)NE * 128 * 4);

  float* out_nf = (float*)d_out;              // (NN, 256)
  float* out_ef = out_nf + (size_t)NN * 256;  // (NE, 128) — also doubles as ef1 staging

  // nf0 = embed_table[node_types]  (NN x 128)
  k_embed<<<(NN*128)/256, 256, 0, stream>>>(node_types, table, nf_buf);

  // Layer 0: in_n=128, in_e=64 -> nf1 (NN x 256) in nf_buf, ef1 (NE x 128) in out_ef
  run_layer(nf_buf, 128, efeats, 64,
            W_src0, b_src0, W_ni0, W_nj0, W_fij0, attn0, bias0,
            src, dst, f_ni, f_nj, h_src, F, logits, m_enc, s, h_new,
            nf_buf, out_ef, stream);

  // Layer 1: in_n=256, in_e=128 -> outputs straight to d_out
  run_layer(nf_buf, 256, out_ef, 128,
            W_src1, b_src1, W_ni1, W_nj1, W_fij1, attn1, bias1,
            src, dst, f_ni, f_nj, h_src, F, logits, m_enc, s, h_new,
            out_nf, out_ef, stream);
}